// Round 2
// baseline (258.930 us; speedup 1.0000x reference)
//
#include <hip/hip_runtime.h>
#include <hip/hip_bf16.h>

// Problem constants (reference: B=2, S=2048, D=1024, H=16, HD=64)
constexpr int Bb = 2, Ss = 2048, Dd = 1024, Hh = 16, HD = 64;
constexpr int Mrows = Bb * Ss;                 // 4096 rows for projections
constexpr float QSCALE = 0.125f * 1.44269504088896f;  // 1/sqrt(HD) * log2(e), folded into Q
constexpr size_t CTX_ELEMS = (size_t)Bb * Hh * Ss * HD;  // 4194304

typedef __attribute__((ext_vector_type(8))) short   short8;
typedef __attribute__((ext_vector_type(4))) float   floatx4;
typedef __attribute__((ext_vector_type(8))) __bf16  bf16x8;

#define DEVI __device__ __forceinline__

DEVI unsigned short f2bf(float f) {
  union { float f; unsigned u; } x; x.f = f;
  return (unsigned short)((x.u + 0x7fffu + ((x.u >> 16) & 1u)) >> 16);   // RNE
}
DEVI float fexp2(float x) {
#if __has_builtin(__builtin_amdgcn_exp2f)
  return __builtin_amdgcn_exp2f(x);
#else
  return __expf(x * 0.6931471805599453f);
#endif
}

// ---------------------------------------------------------------------------
// Projection GEMM.  Y = X @ W^T + bias (scaled), bf16 out.
//  SWAP=false: out[b][h][s][hd]  (row-major Y reshaped to [B,H,S,HD])
//  SWAP=true : out_t[n][m] = Y[m][n]   (transposed store, for V)
// Tile 128x128, BK=32, 4 waves; LDS rows padded to 40 shorts.
// ---------------------------------------------------------------------------
constexpr int APAD = 40;

template<bool SWAP>
__global__ __launch_bounds__(256, 2) void proj_gemm(
    const float* __restrict__ X, const float* __restrict__ W,
    const float* __restrict__ bias, unsigned short* __restrict__ out,
    float oscale)
{
  __shared__ __align__(16) unsigned short As[128 * APAD];
  __shared__ __align__(16) unsigned short Bs[128 * APAD];

  const int t    = threadIdx.x;
  const int bm   = blockIdx.x >> 3;      // 32 m-blocks
  const int bn   = blockIdx.x & 7;       // 8 n-blocks
  const int wid  = t >> 6, lane = t & 63;
  const int lrow = lane & 15, lg = lane >> 4;
  const int wm   = (wid >> 1) * 64, wn = (wid & 1) * 64;

  floatx4 acc[4][4];
  #pragma unroll
  for (int i = 0; i < 4; ++i)
    #pragma unroll
    for (int j = 0; j < 4; ++j) acc[i][j] = 0.0f;

  for (int k0 = 0; k0 < Dd; k0 += 32) {
    __syncthreads();
    #pragma unroll
    for (int half = 0; half < 2; ++half) {
      const int cidx = t + half * 256;       // 0..511 chunks (8 fp32 each)
      const int r = cidx >> 2, c = cidx & 3;
      {
        const float* ga = X + (size_t)(bm * 128 + r) * Dd + k0 + c * 8;
        const floatx4 x0 = *(const floatx4*)ga;
        const floatx4 x1 = *(const floatx4*)(ga + 4);
        short8 va;
        #pragma unroll
        for (int j = 0; j < 4; ++j) { va[j] = (short)f2bf(x0[j]); va[4+j] = (short)f2bf(x1[j]); }
        *(short8*)&As[r * APAD + c * 8] = va;
      }
      {
        const float* gb = W + (size_t)(bn * 128 + r) * Dd + k0 + c * 8;
        const floatx4 x0 = *(const floatx4*)gb;
        const floatx4 x1 = *(const floatx4*)(gb + 4);
        short8 vb;
        #pragma unroll
        for (int j = 0; j < 4; ++j) { vb[j] = (short)f2bf(x0[j]); vb[4+j] = (short)f2bf(x1[j]); }
        *(short8*)&Bs[r * APAD + c * 8] = vb;
      }
    }
    __syncthreads();

    bf16x8 af[4], bff[4];
    #pragma unroll
    for (int mi = 0; mi < 4; ++mi)
      af[mi] = __builtin_bit_cast(bf16x8, *(const short8*)&As[(wm + mi * 16 + lrow) * APAD + lg * 8]);
    #pragma unroll
    for (int ni = 0; ni < 4; ++ni)
      bff[ni] = __builtin_bit_cast(bf16x8, *(const short8*)&Bs[(wn + ni * 16 + lrow) * APAD + lg * 8]);

    #pragma unroll
    for (int mi = 0; mi < 4; ++mi)
      #pragma unroll
      for (int ni = 0; ni < 4; ++ni) {
        if constexpr (SWAP)
          acc[mi][ni] = __builtin_amdgcn_mfma_f32_16x16x32_bf16(bff[ni], af[mi], acc[mi][ni], 0, 0, 0);
        else
          acc[mi][ni] = __builtin_amdgcn_mfma_f32_16x16x32_bf16(af[mi], bff[ni], acc[mi][ni], 0, 0, 0);
      }
  }

  if constexpr (!SWAP) {
    // C layout: col = lane&15 -> n, row = lg*4+r -> m.  Store [B,H,S,HD].
    #pragma unroll
    for (int ni = 0; ni < 4; ++ni) {
      const int gcol = bn * 128 + wn + ni * 16 + lrow;
      const float bval = bias[gcol];
      const int h = gcol >> 6, hd = gcol & 63;
      #pragma unroll
      for (int mi = 0; mi < 4; ++mi) {
        #pragma unroll
        for (int r = 0; r < 4; ++r) {
          const int grow = bm * 128 + wm + mi * 16 + lg * 4 + r;   // = b*S + s
          const int b = grow >> 11, s = grow & 2047;
          out[(((size_t)(b * Hh + h) * Ss + s) << 6) + hd] = f2bf((acc[mi][ni][r] + bval) * oscale);
        }
      }
    }
  } else {
    // Swapped C: col = lane&15 -> m (X row), row = lg*4+r -> n (W row). Store Y^T[n][m].
    #pragma unroll
    for (int ni = 0; ni < 4; ++ni) {
      #pragma unroll
      for (int r = 0; r < 4; ++r) {
        const int n = bn * 128 + wn + ni * 16 + lg * 4 + r;
        const float bval = bias[n];
        #pragma unroll
        for (int mi = 0; mi < 4; ++mi) {
          const int m = bm * 128 + wm + mi * 16 + lrow;
          out[(size_t)n * Mrows + m] = f2bf(acc[mi][ni][r] + bval);
        }
      }
    }
  }
}

// ---------------------------------------------------------------------------
// Flash attention (no-max softmax, scores pre-scaled to log2 domain in Q).
// Block = (b,h, 128 q-rows), 4 waves x 32 q-rows.  K & V^T double-buffered in
// LDS (pad-72 rows), P per-wave LDS round-trip, denominators via ones-MFMA.
// Writes context [B,H,S,HD] (fp32) and attn_output [B,S,D] (fp32).
// ---------------------------------------------------------------------------
constexpr int KPAD  = 72;   // shorts per 64-wide LDS row (64 data + 8 pad)
constexpr int PWPAD = 72;

__global__ __launch_bounds__(256, 2) void attn_fwd(
    const unsigned short* __restrict__ ws, float* __restrict__ out)
{
  __shared__ __align__(16) unsigned short Ks[2][64 * KPAD];
  __shared__ __align__(16) unsigned short Vt[2][64 * KPAD];   // rows = hd
  __shared__ __align__(16) unsigned short Pw[4][32 * PWPAD];

  // XCD-bijective swizzle: 512 blocks, 8 XCDs -> 64-block contiguous chunks.
  const int id  = blockIdx.y * 16 + blockIdx.x;
  const int swz = (id & 7) * 64 + (id >> 3);
  const int qb  = swz & 15, bh = swz >> 4;
  const int b   = bh >> 4, h = bh & 15;

  const int t = threadIdx.x, wid = t >> 6, lane = t & 63;
  const int lrow = lane & 15, lg = lane >> 4;
  const unsigned short* Qb = ws + (size_t)bh * (Ss * HD);
  const unsigned short* Kb = ws + (size_t)Mrows * Dd + (size_t)bh * (Ss * HD);
  const unsigned short* Vw = ws + 2 * (size_t)Mrows * Dd;     // [1024][4096]
  const int q0 = qb * 128 + wid * 32;

  // Q fragments in registers for the whole kernel (already scaled by QSCALE)
  bf16x8 qf[2][2];
  #pragma unroll
  for (int qh = 0; qh < 2; ++qh)
    #pragma unroll
    for (int kf = 0; kf < 2; ++kf)
      qf[qh][kf] = __builtin_bit_cast(bf16x8,
          *(const short8*)(Qb + (size_t)(q0 + qh * 16 + lrow) * 64 + kf * 32 + lg * 8));

  floatx4 ctx[2][4];
  floatx4 l4[2];
  #pragma unroll
  for (int qh = 0; qh < 2; ++qh) {
    l4[qh] = 0.0f;
    #pragma unroll
    for (int ni = 0; ni < 4; ++ni) ctx[qh][ni] = 0.0f;
  }
  short8 ones_s;
  #pragma unroll
  for (int j = 0; j < 8; ++j) ones_s[j] = (short)0x3F80;      // bf16 1.0
  const bf16x8 ones = __builtin_bit_cast(bf16x8, ones_s);

  const int sr = t >> 2, sc = t & 3;
  const unsigned short* kgp = Kb + (size_t)sr * 64;                         // + kv0*64 + c*8
  const unsigned short* vgp = Vw + (size_t)(h * 64 + sr) * Mrows + b * Ss;  // + kv0 + c*8

  short8 kreg[2], vreg[2];
  auto stage_load = [&](int kv0) {
    #pragma unroll
    for (int hf = 0; hf < 2; ++hf) {
      const int c = sc + hf * 4;
      kreg[hf] = *(const short8*)(kgp + (size_t)kv0 * 64 + c * 8);
      vreg[hf] = *(const short8*)(vgp + kv0 + c * 8);
    }
  };
  auto stage_write = [&](int buf) {
    #pragma unroll
    for (int hf = 0; hf < 2; ++hf) {
      const int c = sc + hf * 4;
      *(short8*)&Ks[buf][sr * KPAD + c * 8] = kreg[hf];
      *(short8*)&Vt[buf][sr * KPAD + c * 8] = vreg[hf];
    }
  };

  stage_load(0);
  stage_write(0);
  __syncthreads();

  unsigned short* Pme = &Pw[wid][0];

  for (int it = 0; it < Ss / 64; ++it) {
    const int cur = it & 1;
    if (it + 1 < Ss / 64) stage_load((it + 1) * 64);   // prefetch next tile to regs

    // ---- S = Q K^T (log2-domain, pre-scaled) ----
    floatx4 s4[2][4];
    #pragma unroll
    for (int qh = 0; qh < 2; ++qh)
      #pragma unroll
      for (int ni = 0; ni < 4; ++ni) s4[qh][ni] = 0.0f;
    #pragma unroll
    for (int ni = 0; ni < 4; ++ni)
      #pragma unroll
      for (int kf = 0; kf < 2; ++kf) {
        const bf16x8 kfrag = __builtin_bit_cast(bf16x8,
            *(const short8*)&Ks[cur][(ni * 16 + lrow) * KPAD + kf * 32 + lg * 8]);
        #pragma unroll
        for (int qh = 0; qh < 2; ++qh)
          s4[qh][ni] = __builtin_amdgcn_mfma_f32_16x16x32_bf16(qf[qh][kf], kfrag, s4[qh][ni], 0, 0, 0);
      }

    // ---- p = exp2(s), write P tile (wave-local LDS) ----
    #pragma unroll
    for (int qh = 0; qh < 2; ++qh)
      #pragma unroll
      for (int ni = 0; ni < 4; ++ni)
        #pragma unroll
        for (int r = 0; r < 4; ++r) {
          const float p = fexp2(s4[qh][ni][r]);
          Pme[(qh * 16 + lg * 4 + r) * PWPAD + ni * 16 + lrow] = f2bf(p);
        }

    // ---- ctx += P V ; l += P 1  (in-order DS within wave, no barrier) ----
    #pragma unroll
    for (int kvs = 0; kvs < 2; ++kvs) {
      bf16x8 pa[2];
      #pragma unroll
      for (int qh = 0; qh < 2; ++qh) {
        pa[qh] = __builtin_bit_cast(bf16x8,
            *(const short8*)&Pme[(qh * 16 + lrow) * PWPAD + kvs * 32 + lg * 8]);
        l4[qh] = __builtin_amdgcn_mfma_f32_16x16x32_bf16(pa[qh], ones, l4[qh], 0, 0, 0);
      }
      #pragma unroll
      for (int ni = 0; ni < 4; ++ni) {
        const bf16x8 vf = __builtin_bit_cast(bf16x8,
            *(const short8*)&Vt[cur][(ni * 16 + lrow) * KPAD + kvs * 32 + lg * 8]);
        #pragma unroll
        for (int qh = 0; qh < 2; ++qh)
          ctx[qh][ni] = __builtin_amdgcn_mfma_f32_16x16x32_bf16(pa[qh], vf, ctx[qh][ni], 0, 0, 0);
      }
    }

    if (it + 1 < Ss / 64) stage_write(cur ^ 1);        // land prefetch in other buffer
    __syncthreads();                                   // single barrier per tile
  }

  // ---- epilogue: normalize, write both outputs ----
  #pragma unroll
  for (int qh = 0; qh < 2; ++qh) {
    floatx4 inv;
    #pragma unroll
    for (int r = 0; r < 4; ++r) inv[r] = 1.0f / l4[qh][r];
    #pragma unroll
    for (int ni = 0; ni < 4; ++ni) {
      const int hd = ni * 16 + lrow;
      #pragma unroll
      for (int r = 0; r < 4; ++r) {
        const int q = q0 + qh * 16 + lg * 4 + r;
        const float val = ctx[qh][ni][r] * inv[r];
        out[((size_t)bh * Ss + q) * 64 + hd] = val;                             // context
        out[CTX_ELEMS + (((size_t)(b * Ss + q)) << 10) + (h << 6) + hd] = val;  // attn_output
      }
    }
  }
}

// ---------------------------------------------------------------------------
extern "C" void kernel_launch(void* const* d_in, const int* in_sizes, int n_in,
                              void* d_out, int out_size, void* d_ws, size_t ws_size,
                              hipStream_t stream) {
  const float* q  = (const float*)d_in[0];
  const float* k  = (const float*)d_in[1];
  const float* v  = (const float*)d_in[2];
  const float* wq = (const float*)d_in[3];
  const float* bq = (const float*)d_in[4];
  const float* wk = (const float*)d_in[5];
  const float* bk = (const float*)d_in[6];
  const float* wv = (const float*)d_in[7];
  const float* bv = (const float*)d_in[8];
  unsigned short* ws = (unsigned short*)d_ws;   // Q | K | V^T, 3 * 4M bf16 = 24 MB
  float* out = (float*)d_out;

  unsigned short* wsQ = ws;
  unsigned short* wsK = ws + (size_t)Mrows * Dd;
  unsigned short* wsV = ws + 2 * (size_t)Mrows * Dd;

  proj_gemm<false><<<256, 256, 0, stream>>>(q, wq, bq, wsQ, QSCALE);
  proj_gemm<false><<<256, 256, 0, stream>>>(k, wk, bk, wsK, 1.0f);
  proj_gemm<true ><<<256, 256, 0, stream>>>(v, wv, bv, wsV, 1.0f);

  attn_fwd<<<dim3(16, 32), 256, 0, stream>>>(ws, out);
}

// Round 3
// 105.436 us; speedup vs baseline: 2.4558x; 2.4558x over previous
//
#include <hip/hip_runtime.h>
#include <hip/hip_bf16.h>

// Problem constants (reference: B=2, S=2048, D=1024, H=16, HD=64)
constexpr int Bb = 2, Ss = 2048, Dd = 1024, Hh = 16, HD = 64;
constexpr int Mrows = Bb * Ss;                 // 4096
constexpr float QSCALE = 0.125f * 1.44269504088896f;  // 1/sqrt(HD) * log2(e), folded into Q
constexpr size_t CTX_ELEMS = (size_t)Bb * Hh * Ss * HD;

typedef __attribute__((ext_vector_type(8))) short   short8;
typedef __attribute__((ext_vector_type(4))) float   floatx4;
typedef __attribute__((ext_vector_type(8))) __bf16  bf16x8;

#define DEVI __device__ __forceinline__

DEVI unsigned short f2bf(float f) {
  union { float f; unsigned u; } x; x.f = f;
  return (unsigned short)((x.u + 0x7fffu + ((x.u >> 16) & 1u)) >> 16);   // RNE
}
DEVI float fexp2(float x) {
#if __has_builtin(__builtin_amdgcn_exp2f)
  return __builtin_amdgcn_exp2f(x);
#else
  return __expf(x * 0.6931471805599453f);
#endif
}

// workspace layout (bf16 elems), fast path:
constexpr size_t XE = (size_t)Mrows * Dd;      // 4M per X tensor
constexpr size_t WE = (size_t)Dd * Dd;         // 1M per W tensor
constexpr size_t OFF_W = 3 * XE;               // converted weights
constexpr size_t OFF_O = 3 * XE + 3 * WE;      // Q | K | V^T outputs
constexpr size_t WS_NEED = (OFF_O + 3 * XE) * 2;   // 54 MB

// ---------------------------------------------------------------------------
// fp32 -> bf16 conversion pass (6 tensors)
// ---------------------------------------------------------------------------
__global__ __launch_bounds__(256) void convert_bf16(
    const float* __restrict__ q, const float* __restrict__ k, const float* __restrict__ v,
    const float* __restrict__ wq, const float* __restrict__ wk, const float* __restrict__ wv,
    unsigned short* __restrict__ dst)
{
  const int sel = blockIdx.y;
  const float* src; size_t n, off;
  switch (sel) {
    case 0:  src = q;  n = XE; off = 0;            break;
    case 1:  src = k;  n = XE; off = XE;           break;
    case 2:  src = v;  n = XE; off = 2 * XE;       break;
    case 3:  src = wq; n = WE; off = OFF_W;        break;
    case 4:  src = wk; n = WE; off = OFF_W + WE;   break;
    default: src = wv; n = WE; off = OFF_W + 2*WE; break;
  }
  unsigned short* d = dst + off;
  const size_t stride = (size_t)gridDim.x * blockDim.x;
  for (size_t i = (size_t)blockIdx.x * blockDim.x + threadIdx.x; i < n / 8; i += stride) {
    const floatx4 a = *(const floatx4*)(src + i * 8);
    const floatx4 b = *(const floatx4*)(src + i * 8 + 4);
    short8 o;
    #pragma unroll
    for (int j = 0; j < 4; ++j) { o[j] = (short)f2bf(a[j]); o[4 + j] = (short)f2bf(b[j]); }
    *(short8*)(d + i * 8) = o;
  }
}

// ---------------------------------------------------------------------------
// Shared GEMM epilogue.
//  SWAP=false: lane holds (m = wm+mi*16+lg*4+r, n = wn+ni*16+lrow) -> [B,H,S,HD]
//  SWAP=true : lane holds (n = wn+ni*16+lg*4+r, m = wm+mi*16+lrow) -> Y^T[n][m]
// ---------------------------------------------------------------------------
template<bool SWAP>
DEVI void store_out(floatx4 (&acc)[4][4], const float* __restrict__ bias,
                    unsigned short* __restrict__ out, float oscale,
                    int bm, int bn, int wm, int wn, int lrow, int lg)
{
  if constexpr (!SWAP) {
    #pragma unroll
    for (int ni = 0; ni < 4; ++ni) {
      const int gcol = bn * 128 + wn + ni * 16 + lrow;
      const float bval = bias[gcol];
      const int h = gcol >> 6, hd = gcol & 63;
      #pragma unroll
      for (int mi = 0; mi < 4; ++mi)
        #pragma unroll
        for (int r = 0; r < 4; ++r) {
          const int grow = bm * 128 + wm + mi * 16 + lg * 4 + r;   // = b*S + s
          const int b = grow >> 11, s = grow & 2047;
          out[(((size_t)(b * Hh + h) * Ss + s) << 6) + hd] = f2bf((acc[mi][ni][r] + bval) * oscale);
        }
    }
  } else {
    #pragma unroll
    for (int ni = 0; ni < 4; ++ni)
      #pragma unroll
      for (int r = 0; r < 4; ++r) {
        const int n = bn * 128 + wn + ni * 16 + lg * 4 + r;
        const float bval = bias[n];
        #pragma unroll
        for (int mi = 0; mi < 4; ++mi) {
          const int m = bm * 128 + wm + mi * 16 + lrow;
          out[(size_t)n * Mrows + m] = f2bf(acc[mi][ni][r] + bval);
        }
      }
  }
}

// ---------------------------------------------------------------------------
// Fast GEMM core: bf16 inputs, global_load_lds(16B) staging, BK=64, XOR-swizzled
// LDS (linear dest + pre-swizzled global source + swizzled ds_read).
// ---------------------------------------------------------------------------
DEVI void gload16(const unsigned short* g, unsigned short* l) {
  __builtin_amdgcn_global_load_lds(
      (const __attribute__((address_space(1))) unsigned int*)g,
      (__attribute__((address_space(3))) unsigned int*)l, 16, 0, 0);
}

template<bool SWAP>
DEVI void gemm_core_bf16(const unsigned short* __restrict__ X,
                         const unsigned short* __restrict__ W,
                         const float* __restrict__ bias,
                         unsigned short* __restrict__ out, float oscale,
                         unsigned short* As, unsigned short* Bs, int bm, int bn)
{
  const int t = threadIdx.x, wid = t >> 6, lane = t & 63;
  const int lrow = lane & 15, lg = lane >> 4;
  const int wm = (wid >> 1) * 64, wn = (wid & 1) * 64;

  // Staging geometry: wave wid, issue j covers LDS rows (wid*4+j)*8..+8 (linear).
  // Lane l -> row +l/8, 16B chunk c16 = l%8. Source chunk pre-swizzled: c16 ^ (row&7).
  const int srow = lane >> 3;                 // 0..7
  const int gch  = (lane & 7) ^ srow;         // swizzled source chunk
  const unsigned short* gA = X + (size_t)(bm * 128 + wid * 32 + srow) * Dd + gch * 8;
  const unsigned short* gB = W + (size_t)(bn * 128 + wid * 32 + srow) * Dd + gch * 8;
  unsigned short* lA = As + wid * 4 * 512;    // issue j at +j*512 shorts (1KB)
  unsigned short* lB = Bs + wid * 4 * 512;

  floatx4 acc[4][4];
  #pragma unroll
  for (int i = 0; i < 4; ++i)
    #pragma unroll
    for (int j = 0; j < 4; ++j) acc[i][j] = 0.0f;

  for (int k0 = 0; k0 < Dd; k0 += 64) {
    __syncthreads();     // previous iteration's fragment reads complete
    #pragma unroll
    for (int j = 0; j < 4; ++j) {
      gload16(gA + (size_t)j * 8 * Dd + k0, lA + j * 512);
      gload16(gB + (size_t)j * 8 * Dd + k0, lB + j * 512);
    }
    __syncthreads();     // drains vmcnt: staged data visible

    #pragma unroll
    for (int kf = 0; kf < 2; ++kf) {
      bf16x8 af[4], bf[4];
      #pragma unroll
      for (int mi = 0; mi < 4; ++mi) {
        const int row = wm + mi * 16 + lrow;
        const int ch  = ((kf << 2) | lg) ^ (lrow & 7);
        af[mi] = __builtin_bit_cast(bf16x8, *(const short8*)&As[row * 64 + (ch << 3)]);
      }
      #pragma unroll
      for (int ni = 0; ni < 4; ++ni) {
        const int row = wn + ni * 16 + lrow;
        const int ch  = ((kf << 2) | lg) ^ (lrow & 7);
        bf[ni] = __builtin_bit_cast(bf16x8, *(const short8*)&Bs[row * 64 + (ch << 3)]);
      }
      #pragma unroll
      for (int mi = 0; mi < 4; ++mi)
        #pragma unroll
        for (int ni = 0; ni < 4; ++ni) {
          if constexpr (SWAP)
            acc[mi][ni] = __builtin_amdgcn_mfma_f32_16x16x32_bf16(bf[ni], af[mi], acc[mi][ni], 0, 0, 0);
          else
            acc[mi][ni] = __builtin_amdgcn_mfma_f32_16x16x32_bf16(af[mi], bf[ni], acc[mi][ni], 0, 0, 0);
        }
    }
  }
  store_out<SWAP>(acc, bias, out, oscale, bm, bn, wm, wn, lrow, lg);
}

__global__ __launch_bounds__(256, 3) void qkv_gemm_bf16(
    const unsigned short* __restrict__ ws,
    const float* __restrict__ bq, const float* __restrict__ bk, const float* __restrict__ bv,
    unsigned short* __restrict__ outbase)
{
  __shared__ __align__(16) unsigned short As[128 * 64];   // 16 KB, linear [row][64]
  __shared__ __align__(16) unsigned short Bs[128 * 64];

  // XCD-bijective swizzle over 768 blocks (96 contiguous per XCD).
  const int id  = blockIdx.y * 256 + blockIdx.x;
  const int swz = (id & 7) * 96 + (id >> 3);
  const int sel = swz >> 8;                  // 0..2 (Q,K,V)
  const int bx  = swz & 255;
  const int bm = bx >> 3, bn = bx & 7;

  const unsigned short* X = ws + (size_t)sel * XE;
  const unsigned short* W = ws + OFF_W + (size_t)sel * WE;
  const float* bias = sel == 0 ? bq : sel == 1 ? bk : bv;
  unsigned short* out = outbase + (size_t)sel * XE;

  if (sel == 2) gemm_core_bf16<true >(X, W, bias, out, 1.0f,   As, Bs, bm, bn);
  else          gemm_core_bf16<false>(X, W, bias, out, sel == 0 ? QSCALE : 1.0f, As, Bs, bm, bn);
}

// ---------------------------------------------------------------------------
// Fallback GEMM (fp32 inputs, reg-staged + cvt) — used if ws too small.
// ---------------------------------------------------------------------------
constexpr int APAD = 40;

template<bool SWAP>
DEVI void gemm_core_f32(const float* __restrict__ X, const float* __restrict__ W,
                        const float* __restrict__ bias, unsigned short* __restrict__ out,
                        float oscale, unsigned short* As, unsigned short* Bs, int bm, int bn)
{
  const int t = threadIdx.x, wid = t >> 6, lane = t & 63;
  const int lrow = lane & 15, lg = lane >> 4;
  const int wm = (wid >> 1) * 64, wn = (wid & 1) * 64;

  floatx4 acc[4][4];
  #pragma unroll
  for (int i = 0; i < 4; ++i)
    #pragma unroll
    for (int j = 0; j < 4; ++j) acc[i][j] = 0.0f;

  for (int k0 = 0; k0 < Dd; k0 += 32) {
    __syncthreads();
    #pragma unroll
    for (int half = 0; half < 2; ++half) {
      const int cidx = t + half * 256;
      const int r = cidx >> 2, c = cidx & 3;
      {
        const float* ga = X + (size_t)(bm * 128 + r) * Dd + k0 + c * 8;
        const floatx4 x0 = *(const floatx4*)ga;
        const floatx4 x1 = *(const floatx4*)(ga + 4);
        short8 va;
        #pragma unroll
        for (int j = 0; j < 4; ++j) { va[j] = (short)f2bf(x0[j]); va[4+j] = (short)f2bf(x1[j]); }
        *(short8*)&As[r * APAD + c * 8] = va;
      }
      {
        const float* gb = W + (size_t)(bn * 128 + r) * Dd + k0 + c * 8;
        const floatx4 x0 = *(const floatx4*)gb;
        const floatx4 x1 = *(const floatx4*)(gb + 4);
        short8 vb;
        #pragma unroll
        for (int j = 0; j < 4; ++j) { vb[j] = (short)f2bf(x0[j]); vb[4+j] = (short)f2bf(x1[j]); }
        *(short8*)&Bs[r * APAD + c * 8] = vb;
      }
    }
    __syncthreads();

    bf16x8 af[4], bf[4];
    #pragma unroll
    for (int mi = 0; mi < 4; ++mi)
      af[mi] = __builtin_bit_cast(bf16x8, *(const short8*)&As[(wm + mi * 16 + lrow) * APAD + lg * 8]);
    #pragma unroll
    for (int ni = 0; ni < 4; ++ni)
      bf[ni] = __builtin_bit_cast(bf16x8, *(const short8*)&Bs[(wn + ni * 16 + lrow) * APAD + lg * 8]);

    #pragma unroll
    for (int mi = 0; mi < 4; ++mi)
      #pragma unroll
      for (int ni = 0; ni < 4; ++ni) {
        if constexpr (SWAP)
          acc[mi][ni] = __builtin_amdgcn_mfma_f32_16x16x32_bf16(bf[ni], af[mi], acc[mi][ni], 0, 0, 0);
        else
          acc[mi][ni] = __builtin_amdgcn_mfma_f32_16x16x32_bf16(af[mi], bf[ni], acc[mi][ni], 0, 0, 0);
      }
  }
  store_out<SWAP>(acc, bias, out, oscale, bm, bn, wm, wn, lrow, lg);
}

__global__ __launch_bounds__(256, 2) void qkv_gemm_f32(
    const float* __restrict__ q, const float* __restrict__ k, const float* __restrict__ v,
    const float* __restrict__ wq, const float* __restrict__ wk, const float* __restrict__ wv,
    const float* __restrict__ bq, const float* __restrict__ bk, const float* __restrict__ bv,
    unsigned short* __restrict__ outbase)
{
  __shared__ __align__(16) unsigned short As[128 * APAD];
  __shared__ __align__(16) unsigned short Bs[128 * APAD];

  const int id  = blockIdx.y * 256 + blockIdx.x;
  const int swz = (id & 7) * 96 + (id >> 3);
  const int sel = swz >> 8;
  const int bx  = swz & 255;
  const int bm = bx >> 3, bn = bx & 7;

  const float* X = sel == 0 ? q : sel == 1 ? k : v;
  const float* W = sel == 0 ? wq : sel == 1 ? wk : wv;
  const float* bias = sel == 0 ? bq : sel == 1 ? bk : bv;
  unsigned short* out = outbase + (size_t)sel * XE;

  if (sel == 2) gemm_core_f32<true >(X, W, bias, out, 1.0f, As, Bs, bm, bn);
  else          gemm_core_f32<false>(X, W, bias, out, sel == 0 ? QSCALE : 1.0f, As, Bs, bm, bn);
}

// ---------------------------------------------------------------------------
// Flash attention (unchanged from round 2 except base pointers as args).
// ---------------------------------------------------------------------------
constexpr int KPAD  = 72;
constexpr int PWPAD = 72;

__global__ __launch_bounds__(256, 2) void attn_fwd(
    const unsigned short* __restrict__ Qw, const unsigned short* __restrict__ Kw,
    const unsigned short* __restrict__ Vw, float* __restrict__ out)
{
  __shared__ __align__(16) unsigned short Ks[2][64 * KPAD];
  __shared__ __align__(16) unsigned short Vt[2][64 * KPAD];
  __shared__ __align__(16) unsigned short Pw[4][32 * PWPAD];

  const int id  = blockIdx.y * 16 + blockIdx.x;
  const int swz = (id & 7) * 64 + (id >> 3);
  const int qb  = swz & 15, bh = swz >> 4;
  const int b   = bh >> 4, h = bh & 15;

  const int t = threadIdx.x, wid = t >> 6, lane = t & 63;
  const int lrow = lane & 15, lg = lane >> 4;
  const unsigned short* Qb = Qw + (size_t)bh * (Ss * HD);
  const unsigned short* Kb = Kw + (size_t)bh * (Ss * HD);
  const int q0 = qb * 128 + wid * 32;

  bf16x8 qf[2][2];
  #pragma unroll
  for (int qh = 0; qh < 2; ++qh)
    #pragma unroll
    for (int kf = 0; kf < 2; ++kf)
      qf[qh][kf] = __builtin_bit_cast(bf16x8,
          *(const short8*)(Qb + (size_t)(q0 + qh * 16 + lrow) * 64 + kf * 32 + lg * 8));

  floatx4 ctx[2][4];
  floatx4 l4[2];
  #pragma unroll
  for (int qh = 0; qh < 2; ++qh) {
    l4[qh] = 0.0f;
    #pragma unroll
    for (int ni = 0; ni < 4; ++ni) ctx[qh][ni] = 0.0f;
  }
  short8 ones_s;
  #pragma unroll
  for (int j = 0; j < 8; ++j) ones_s[j] = (short)0x3F80;
  const bf16x8 ones = __builtin_bit_cast(bf16x8, ones_s);

  const int sr = t >> 2, sc = t & 3;
  const unsigned short* kgp = Kb + (size_t)sr * 64;
  const unsigned short* vgp = Vw + (size_t)(h * 64 + sr) * Mrows + b * Ss;

  short8 kreg[2], vreg[2];
  auto stage_load = [&](int kv0) {
    #pragma unroll
    for (int hf = 0; hf < 2; ++hf) {
      const int c = sc + hf * 4;
      kreg[hf] = *(const short8*)(kgp + (size_t)kv0 * 64 + c * 8);
      vreg[hf] = *(const short8*)(vgp + kv0 + c * 8);
    }
  };
  auto stage_write = [&](int buf) {
    #pragma unroll
    for (int hf = 0; hf < 2; ++hf) {
      const int c = sc + hf * 4;
      *(short8*)&Ks[buf][sr * KPAD + c * 8] = kreg[hf];
      *(short8*)&Vt[buf][sr * KPAD + c * 8] = vreg[hf];
    }
  };

  stage_load(0);
  stage_write(0);
  __syncthreads();

  unsigned short* Pme = &Pw[wid][0];

  for (int it = 0; it < Ss / 64; ++it) {
    const int cur = it & 1;
    if (it + 1 < Ss / 64) stage_load((it + 1) * 64);

    floatx4 s4[2][4];
    #pragma unroll
    for (int qh = 0; qh < 2; ++qh)
      #pragma unroll
      for (int ni = 0; ni < 4; ++ni) s4[qh][ni] = 0.0f;
    #pragma unroll
    for (int ni = 0; ni < 4; ++ni)
      #pragma unroll
      for (int kf = 0; kf < 2; ++kf) {
        const bf16x8 kfrag = __builtin_bit_cast(bf16x8,
            *(const short8*)&Ks[cur][(ni * 16 + lrow) * KPAD + kf * 32 + lg * 8]);
        #pragma unroll
        for (int qh = 0; qh < 2; ++qh)
          s4[qh][ni] = __builtin_amdgcn_mfma_f32_16x16x32_bf16(qf[qh][kf], kfrag, s4[qh][ni], 0, 0, 0);
      }

    #pragma unroll
    for (int qh = 0; qh < 2; ++qh)
      #pragma unroll
      for (int ni = 0; ni < 4; ++ni)
        #pragma unroll
        for (int r = 0; r < 4; ++r) {
          const float p = fexp2(s4[qh][ni][r]);
          Pme[(qh * 16 + lg * 4 + r) * PWPAD + ni * 16 + lrow] = f2bf(p);
        }

    #pragma unroll
    for (int kvs = 0; kvs < 2; ++kvs) {
      bf16x8 pa[2];
      #pragma unroll
      for (int qh = 0; qh < 2; ++qh) {
        pa[qh] = __builtin_bit_cast(bf16x8,
            *(const short8*)&Pme[(qh * 16 + lrow) * PWPAD + kvs * 32 + lg * 8]);
        l4[qh] = __builtin_amdgcn_mfma_f32_16x16x32_bf16(pa[qh], ones, l4[qh], 0, 0, 0);
      }
      #pragma unroll
      for (int ni = 0; ni < 4; ++ni) {
        const bf16x8 vf = __builtin_bit_cast(bf16x8,
            *(const short8*)&Vt[cur][(ni * 16 + lrow) * KPAD + kvs * 32 + lg * 8]);
        #pragma unroll
        for (int qh = 0; qh < 2; ++qh)
          ctx[qh][ni] = __builtin_amdgcn_mfma_f32_16x16x32_bf16(pa[qh], vf, ctx[qh][ni], 0, 0, 0);
      }
    }

    if (it + 1 < Ss / 64) stage_write(cur ^ 1);
    __syncthreads();
  }

  #pragma unroll
  for (int qh = 0; qh < 2; ++qh) {
    floatx4 inv;
    #pragma unroll
    for (int r = 0; r < 4; ++r) inv[r] = 1.0f / l4[qh][r];
    #pragma unroll
    for (int ni = 0; ni < 4; ++ni) {
      const int hd = ni * 16 + lrow;
      #pragma unroll
      for (int r = 0; r < 4; ++r) {
        const int q = q0 + qh * 16 + lg * 4 + r;
        const float val = ctx[qh][ni][r] * inv[r];
        out[((size_t)bh * Ss + q) * 64 + hd] = val;
        out[CTX_ELEMS + (((size_t)(b * Ss + q)) << 10) + (h << 6) + hd] = val;
      }
    }
  }
}

// ---------------------------------------------------------------------------
extern "C" void kernel_launch(void* const* d_in, const int* in_sizes, int n_in,
                              void* d_out, int out_size, void* d_ws, size_t ws_size,
                              hipStream_t stream) {
  const float* q  = (const float*)d_in[0];
  const float* k  = (const float*)d_in[1];
  const float* v  = (const float*)d_in[2];
  const float* wq = (const float*)d_in[3];
  const float* bq = (const float*)d_in[4];
  const float* wk = (const float*)d_in[5];
  const float* bk = (const float*)d_in[6];
  const float* wv = (const float*)d_in[7];
  const float* bv = (const float*)d_in[8];
  unsigned short* ws = (unsigned short*)d_ws;
  float* out = (float*)d_out;

  if (ws_size >= WS_NEED) {
    convert_bf16<<<dim3(256, 6), 256, 0, stream>>>(q, k, v, wq, wk, wv, ws);
    qkv_gemm_bf16<<<dim3(256, 3), 256, 0, stream>>>(ws, bq, bk, bv, ws + OFF_O);
    attn_fwd<<<dim3(16, 32), 256, 0, stream>>>(ws + OFF_O, ws + OFF_O + XE, ws + OFF_O + 2 * XE, out);
  } else {
    qkv_gemm_f32<<<dim3(256, 3), 256, 0, stream>>>(q, k, v, wq, wk, wv, bq, bk, bv, ws);
    attn_fwd<<<dim3(16, 32), 256, 0, stream>>>(ws, ws + XE, ws + 2 * XE, out);
  }
}

// Round 4
// 92.969 us; speedup vs baseline: 2.7851x; 1.1341x over previous
//
#include <hip/hip_runtime.h>
#include <hip/hip_bf16.h>

// Problem constants (reference: B=2, S=2048, D=1024, H=16, HD=64)
constexpr int Bb = 2, Ss = 2048, Dd = 1024, Hh = 16, HD = 64;
constexpr int Mrows = Bb * Ss;                 // 4096
constexpr float QSCALE = 0.125f * 1.44269504088896f;  // 1/sqrt(HD) * log2(e), folded into Q
constexpr size_t CTX_ELEMS = (size_t)Bb * Hh * Ss * HD;

typedef __attribute__((ext_vector_type(8)))  short        short8;
typedef __attribute__((ext_vector_type(4)))  float        floatx4;
typedef __attribute__((ext_vector_type(16))) float        floatx16;
typedef __attribute__((ext_vector_type(4)))  unsigned int uintx4;
typedef __attribute__((ext_vector_type(8)))  __bf16       bf16x8;

#define DEVI __device__ __forceinline__

DEVI unsigned short f2bf(float f) {
  union { float f; unsigned u; } x; x.f = f;
  return (unsigned short)((x.u + 0x7fffu + ((x.u >> 16) & 1u)) >> 16);   // RNE
}
DEVI float fexp2(float x) {
#if __has_builtin(__builtin_amdgcn_exp2f)
  return __builtin_amdgcn_exp2f(x);
#else
  return __expf(x * 0.6931471805599453f);
#endif
}

// workspace layout (bf16 elems), fast path:
constexpr size_t XE = (size_t)Mrows * Dd;      // 4M per X tensor
constexpr size_t WE = (size_t)Dd * Dd;         // 1M per W tensor
constexpr size_t OFF_W = 3 * XE;               // converted weights
constexpr size_t OFF_O = 3 * XE + 3 * WE;      // Q | K | V^T outputs
constexpr size_t WS_NEED = (OFF_O + 3 * XE) * 2;   // 54 MB

// ---------------------------------------------------------------------------
// fp32 -> bf16 conversion pass (6 tensors)
// ---------------------------------------------------------------------------
__global__ __launch_bounds__(256) void convert_bf16(
    const float* __restrict__ q, const float* __restrict__ k, const float* __restrict__ v,
    const float* __restrict__ wq, const float* __restrict__ wk, const float* __restrict__ wv,
    unsigned short* __restrict__ dst)
{
  const int sel = blockIdx.y;
  const float* src; size_t n, off;
  switch (sel) {
    case 0:  src = q;  n = XE; off = 0;            break;
    case 1:  src = k;  n = XE; off = XE;           break;
    case 2:  src = v;  n = XE; off = 2 * XE;       break;
    case 3:  src = wq; n = WE; off = OFF_W;        break;
    case 4:  src = wk; n = WE; off = OFF_W + WE;   break;
    default: src = wv; n = WE; off = OFF_W + 2*WE; break;
  }
  unsigned short* d = dst + off;
  const size_t stride = (size_t)gridDim.x * blockDim.x;
  for (size_t i = (size_t)blockIdx.x * blockDim.x + threadIdx.x; i < n / 8; i += stride) {
    const floatx4 a = *(const floatx4*)(src + i * 8);
    const floatx4 b = *(const floatx4*)(src + i * 8 + 4);
    short8 o;
    #pragma unroll
    for (int j = 0; j < 4; ++j) { o[j] = (short)f2bf(a[j]); o[4 + j] = (short)f2bf(b[j]); }
    *(short8*)(d + i * 8) = o;
  }
}

// ---------------------------------------------------------------------------
// Shared GEMM epilogue (16x16 layout).
// ---------------------------------------------------------------------------
template<bool SWAP>
DEVI void store_out(floatx4 (&acc)[4][4], const float* __restrict__ bias,
                    unsigned short* __restrict__ out, float oscale,
                    int bm, int bn, int wm, int wn, int lrow, int lg)
{
  if constexpr (!SWAP) {
    #pragma unroll
    for (int ni = 0; ni < 4; ++ni) {
      const int gcol = bn * 128 + wn + ni * 16 + lrow;
      const float bval = bias[gcol];
      const int h = gcol >> 6, hd = gcol & 63;
      #pragma unroll
      for (int mi = 0; mi < 4; ++mi)
        #pragma unroll
        for (int r = 0; r < 4; ++r) {
          const int grow = bm * 128 + wm + mi * 16 + lg * 4 + r;   // = b*S + s
          const int b = grow >> 11, s = grow & 2047;
          out[(((size_t)(b * Hh + h) * Ss + s) << 6) + hd] = f2bf((acc[mi][ni][r] + bval) * oscale);
        }
    }
  } else {
    #pragma unroll
    for (int ni = 0; ni < 4; ++ni)
      #pragma unroll
      for (int r = 0; r < 4; ++r) {
        const int n = bn * 128 + wn + ni * 16 + lg * 4 + r;
        const float bval = bias[n];
        #pragma unroll
        for (int mi = 0; mi < 4; ++mi) {
          const int m = bm * 128 + wm + mi * 16 + lrow;
          out[(size_t)n * Mrows + m] = f2bf(acc[mi][ni][r] + bval);
        }
      }
  }
}

// ---------------------------------------------------------------------------
// Fast GEMM core (unchanged from round 3): global_load_lds(16B), BK=64,
// XOR-swizzled LDS via pre-swizzled source.
// ---------------------------------------------------------------------------
DEVI void gload16(const unsigned short* g, unsigned short* l) {
  __builtin_amdgcn_global_load_lds(
      (const __attribute__((address_space(1))) unsigned int*)g,
      (__attribute__((address_space(3))) unsigned int*)l, 16, 0, 0);
}

template<bool SWAP>
DEVI void gemm_core_bf16(const unsigned short* __restrict__ X,
                         const unsigned short* __restrict__ W,
                         const float* __restrict__ bias,
                         unsigned short* __restrict__ out, float oscale,
                         unsigned short* As, unsigned short* Bs, int bm, int bn)
{
  const int t = threadIdx.x, wid = t >> 6, lane = t & 63;
  const int lrow = lane & 15, lg = lane >> 4;
  const int wm = (wid >> 1) * 64, wn = (wid & 1) * 64;

  const int srow = lane >> 3;
  const int gch  = (lane & 7) ^ srow;
  const unsigned short* gA = X + (size_t)(bm * 128 + wid * 32 + srow) * Dd + gch * 8;
  const unsigned short* gB = W + (size_t)(bn * 128 + wid * 32 + srow) * Dd + gch * 8;
  unsigned short* lA = As + wid * 4 * 512;
  unsigned short* lB = Bs + wid * 4 * 512;

  floatx4 acc[4][4];
  #pragma unroll
  for (int i = 0; i < 4; ++i)
    #pragma unroll
    for (int j = 0; j < 4; ++j) acc[i][j] = 0.0f;

  for (int k0 = 0; k0 < Dd; k0 += 64) {
    __syncthreads();
    #pragma unroll
    for (int j = 0; j < 4; ++j) {
      gload16(gA + (size_t)j * 8 * Dd + k0, lA + j * 512);
      gload16(gB + (size_t)j * 8 * Dd + k0, lB + j * 512);
    }
    __syncthreads();

    #pragma unroll
    for (int kf = 0; kf < 2; ++kf) {
      bf16x8 af[4], bf[4];
      #pragma unroll
      for (int mi = 0; mi < 4; ++mi) {
        const int row = wm + mi * 16 + lrow;
        const int ch  = ((kf << 2) | lg) ^ (lrow & 7);
        af[mi] = __builtin_bit_cast(bf16x8, *(const short8*)&As[row * 64 + (ch << 3)]);
      }
      #pragma unroll
      for (int ni = 0; ni < 4; ++ni) {
        const int row = wn + ni * 16 + lrow;
        const int ch  = ((kf << 2) | lg) ^ (lrow & 7);
        bf[ni] = __builtin_bit_cast(bf16x8, *(const short8*)&Bs[row * 64 + (ch << 3)]);
      }
      #pragma unroll
      for (int mi = 0; mi < 4; ++mi)
        #pragma unroll
        for (int ni = 0; ni < 4; ++ni) {
          if constexpr (SWAP)
            acc[mi][ni] = __builtin_amdgcn_mfma_f32_16x16x32_bf16(bf[ni], af[mi], acc[mi][ni], 0, 0, 0);
          else
            acc[mi][ni] = __builtin_amdgcn_mfma_f32_16x16x32_bf16(af[mi], bf[ni], acc[mi][ni], 0, 0, 0);
        }
    }
  }
  store_out<SWAP>(acc, bias, out, oscale, bm, bn, wm, wn, lrow, lg);
}

__global__ __launch_bounds__(256, 3) void qkv_gemm_bf16(
    const unsigned short* __restrict__ ws,
    const float* __restrict__ bq, const float* __restrict__ bk, const float* __restrict__ bv,
    unsigned short* __restrict__ outbase)
{
  __shared__ __align__(16) unsigned short As[128 * 64];
  __shared__ __align__(16) unsigned short Bs[128 * 64];

  const int id  = blockIdx.y * 256 + blockIdx.x;
  const int swz = (id & 7) * 96 + (id >> 3);
  const int sel = swz >> 8;
  const int bx  = swz & 255;
  const int bm = bx >> 3, bn = bx & 7;

  const unsigned short* X = ws + (size_t)sel * XE;
  const unsigned short* W = ws + OFF_W + (size_t)sel * WE;
  const float* bias = sel == 0 ? bq : sel == 1 ? bk : bv;
  unsigned short* out = outbase + (size_t)sel * XE;

  if (sel == 2) gemm_core_bf16<true >(X, W, bias, out, 1.0f,   As, Bs, bm, bn);
  else          gemm_core_bf16<false>(X, W, bias, out, sel == 0 ? QSCALE : 1.0f, As, Bs, bm, bn);
}

// ---------------------------------------------------------------------------
// Fallback GEMM (fp32 inputs) — used if ws too small.
// ---------------------------------------------------------------------------
constexpr int APAD = 40;

template<bool SWAP>
DEVI void gemm_core_f32(const float* __restrict__ X, const float* __restrict__ W,
                        const float* __restrict__ bias, unsigned short* __restrict__ out,
                        float oscale, unsigned short* As, unsigned short* Bs, int bm, int bn)
{
  const int t = threadIdx.x, wid = t >> 6, lane = t & 63;
  const int lrow = lane & 15, lg = lane >> 4;
  const int wm = (wid >> 1) * 64, wn = (wid & 1) * 64;

  floatx4 acc[4][4];
  #pragma unroll
  for (int i = 0; i < 4; ++i)
    #pragma unroll
    for (int j = 0; j < 4; ++j) acc[i][j] = 0.0f;

  for (int k0 = 0; k0 < Dd; k0 += 32) {
    __syncthreads();
    #pragma unroll
    for (int half = 0; half < 2; ++half) {
      const int cidx = t + half * 256;
      const int r = cidx >> 2, c = cidx & 3;
      {
        const float* ga = X + (size_t)(bm * 128 + r) * Dd + k0 + c * 8;
        const floatx4 x0 = *(const floatx4*)ga;
        const floatx4 x1 = *(const floatx4*)(ga + 4);
        short8 va;
        #pragma unroll
        for (int j = 0; j < 4; ++j) { va[j] = (short)f2bf(x0[j]); va[4+j] = (short)f2bf(x1[j]); }
        *(short8*)&As[r * APAD + c * 8] = va;
      }
      {
        const float* gb = W + (size_t)(bn * 128 + r) * Dd + k0 + c * 8;
        const floatx4 x0 = *(const floatx4*)gb;
        const floatx4 x1 = *(const floatx4*)(gb + 4);
        short8 vb;
        #pragma unroll
        for (int j = 0; j < 4; ++j) { vb[j] = (short)f2bf(x0[j]); vb[4+j] = (short)f2bf(x1[j]); }
        *(short8*)&Bs[r * APAD + c * 8] = vb;
      }
    }
    __syncthreads();

    bf16x8 af[4], bf[4];
    #pragma unroll
    for (int mi = 0; mi < 4; ++mi)
      af[mi] = __builtin_bit_cast(bf16x8, *(const short8*)&As[(wm + mi * 16 + lrow) * APAD + lg * 8]);
    #pragma unroll
    for (int ni = 0; ni < 4; ++ni)
      bf[ni] = __builtin_bit_cast(bf16x8, *(const short8*)&Bs[(wn + ni * 16 + lrow) * APAD + lg * 8]);

    #pragma unroll
    for (int mi = 0; mi < 4; ++mi)
      #pragma unroll
      for (int ni = 0; ni < 4; ++ni) {
        if constexpr (SWAP)
          acc[mi][ni] = __builtin_amdgcn_mfma_f32_16x16x32_bf16(bf[ni], af[mi], acc[mi][ni], 0, 0, 0);
        else
          acc[mi][ni] = __builtin_amdgcn_mfma_f32_16x16x32_bf16(af[mi], bf[ni], acc[mi][ni], 0, 0, 0);
      }
  }
  store_out<SWAP>(acc, bias, out, oscale, bm, bn, wm, wn, lrow, lg);
}

__global__ __launch_bounds__(256, 2) void qkv_gemm_f32(
    const float* __restrict__ q, const float* __restrict__ k, const float* __restrict__ v,
    const float* __restrict__ wq, const float* __restrict__ wk, const float* __restrict__ wv,
    const float* __restrict__ bq, const float* __restrict__ bk, const float* __restrict__ bv,
    unsigned short* __restrict__ outbase)
{
  __shared__ __align__(16) unsigned short As[128 * APAD];
  __shared__ __align__(16) unsigned short Bs[128 * APAD];

  const int id  = blockIdx.y * 256 + blockIdx.x;
  const int swz = (id & 7) * 96 + (id >> 3);
  const int sel = swz >> 8;
  const int bx  = swz & 255;
  const int bm = bx >> 3, bn = bx & 7;

  const float* X = sel == 0 ? q : sel == 1 ? k : v;
  const float* W = sel == 0 ? wq : sel == 1 ? wk : wv;
  const float* bias = sel == 0 ? bq : sel == 1 ? bk : bv;
  unsigned short* out = outbase + (size_t)sel * XE;

  if (sel == 2) gemm_core_f32<true >(X, W, bias, out, 1.0f, As, Bs, bm, bn);
  else          gemm_core_f32<false>(X, W, bias, out, sel == 0 ? QSCALE : 1.0f, As, Bs, bm, bn);
}

// ---------------------------------------------------------------------------
// Flash attention, 32x32 MFMA, fully in-register softmax.
// Block = (b,h, 128 q), 4 waves x 32 q.  K and V^T staged via global_load_lds
// into XOR-swizzled linear [64][64] LDS tiles (double-buffered, 1 barrier/tile).
// Swapped QK^T (mfma(K,Q)) -> per-lane P row; cvt_pk_bf16 + permlane32_swap
// builds PV A-fragments in-register.  Denominator via ones-MFMA (ctx layout).
// ---------------------------------------------------------------------------
__global__ __launch_bounds__(256, 2) void attn_fwd(
    const unsigned short* __restrict__ Qw, const unsigned short* __restrict__ Kw,
    const unsigned short* __restrict__ Vw, float* __restrict__ out)
{
  __shared__ __align__(16) unsigned short Ks[2][64 * 64];   // [kv][hd], chunk^=(kv&7)
  __shared__ __align__(16) unsigned short Vt[2][64 * 64];   // [hd][kv], chunk^=(hd&7)

  // XCD-bijective swizzle: 512 blocks -> 64-contiguous per XCD.
  const int id  = blockIdx.y * 16 + blockIdx.x;
  const int swz = (id & 7) * 64 + (id >> 3);
  const int qb  = swz & 15, bh = swz >> 4;
  const int b   = bh >> 4, h = bh & 15;

  const int t = threadIdx.x, wid = t >> 6, lane = t & 63;
  const int l31 = lane & 31, hi = lane >> 5;
  const unsigned short* Qb = Qw + (size_t)bh * (Ss * HD);
  const unsigned short* Kb = Kw + (size_t)bh * (Ss * HD);
  const unsigned short* Vg = Vw + (size_t)(h * 64) * Mrows + b * Ss;   // row=hd
  const int q0 = qb * 128 + wid * 32;

  // Q B-fragments: lane holds Q[q=l31][hd = hs*16 + hi*8 + j]
  bf16x8 qf[4];
  #pragma unroll
  for (int hs = 0; hs < 4; ++hs)
    qf[hs] = __builtin_bit_cast(bf16x8,
        *(const short8*)(Qb + (size_t)(q0 + l31) * 64 + hs * 16 + hi * 8));

  floatx16 ctx[2], lsum;
  #pragma unroll
  for (int nb = 0; nb < 2; ++nb) ctx[nb] = 0.0f;
  lsum = 0.0f;

  short8 ones_s;
  #pragma unroll
  for (int j = 0; j < 8; ++j) ones_s[j] = (short)0x3F80;   // bf16 1.0
  const bf16x8 ones = __builtin_bit_cast(bf16x8, ones_s);

  // Staging: wave wid covers rows wid*16 .. wid*16+15 of both tensors.
  const int rl = lane >> 3;                  // 0..7 within 8-row group
  const int cs = (lane & 7) ^ rl;            // pre-swizzled source chunk
  auto stage = [&](int kv0, int buf) {
    #pragma unroll
    for (int i = 0; i < 2; ++i) {
      const int row = wid * 16 + i * 8 + rl;
      gload16(Kb + (size_t)(kv0 + row) * 64 + cs * 8, &Ks[buf][(wid * 16 + i * 8) * 64]);
      gload16(Vg + (size_t)row * Mrows + kv0 + cs * 8, &Vt[buf][(wid * 16 + i * 8) * 64]);
    }
  };

  stage(0, 0);

  for (int it = 0; it < Ss / 64; ++it) {
    const int cur = it & 1;
    __syncthreads();                          // drains vmcnt: staged tile visible
    if (it + 1 < Ss / 64) stage((it + 1) * 64, cur ^ 1);

    // ---- S^T = K Q^T : per kvb, 4 hd-step MFMAs.  col=q=l31, row=kv. ----
    floatx16 s[2];
    s[0] = 0.0f; s[1] = 0.0f;
    __builtin_amdgcn_s_setprio(1);
    #pragma unroll
    for (int kvb = 0; kvb < 2; ++kvb)
      #pragma unroll
      for (int hs = 0; hs < 4; ++hs) {
        const int ch = ((hs << 1) | hi) ^ (l31 & 7);
        const bf16x8 kf = __builtin_bit_cast(bf16x8,
            *(const short8*)&Ks[cur][(kvb * 32 + l31) * 64 + (ch << 3)]);
        s[kvb] = __builtin_amdgcn_mfma_f32_32x32x16_bf16(kf, qf[hs], s[kvb], 0, 0, 0);
      }
    __builtin_amdgcn_s_setprio(0);

    // ---- per kvb: exp2 -> pack bf16 pairs -> permlane half-swap -> PV ----
    #pragma unroll
    for (int kvb = 0; kvb < 2; ++kvb) {
      float p[16];
      #pragma unroll
      for (int r = 0; r < 16; ++r) p[r] = fexp2(s[kvb][r]);
      unsigned int c[8];
      #pragma unroll
      for (int i = 0; i < 8; ++i)
        asm("v_cvt_pk_bf16_f32 %0, %1, %2" : "=v"(c[i]) : "v"(p[2 * i]), "v"(p[2 * i + 1]));

      #pragma unroll
      for (int ks2 = 0; ks2 < 2; ++ks2) {
        unsigned int w0 = c[4 * ks2 + 0], w2 = c[4 * ks2 + 2];
        unsigned int w1 = c[4 * ks2 + 1], w3 = c[4 * ks2 + 3];
        asm("v_permlane32_swap_b32 %0, %1" : "+v"(w0), "+v"(w2));
        asm("v_permlane32_swap_b32 %0, %1" : "+v"(w1), "+v"(w3));
        uintx4 paw; paw[0] = w0; paw[1] = w1; paw[2] = w2; paw[3] = w3;
        const bf16x8 pa = __builtin_bit_cast(bf16x8, paw);

        const int ks = kvb * 2 + ks2;         // 16-kv step within tile
        __builtin_amdgcn_s_setprio(1);
        lsum = __builtin_amdgcn_mfma_f32_32x32x16_bf16(pa, ones, lsum, 0, 0, 0);
        #pragma unroll
        for (int nb = 0; nb < 2; ++nb) {
          const int ch = ((ks << 1) | hi) ^ (l31 & 7);
          const bf16x8 vf = __builtin_bit_cast(bf16x8,
              *(const short8*)&Vt[cur][(nb * 32 + l31) * 64 + (ch << 3)]);
          ctx[nb] = __builtin_amdgcn_mfma_f32_32x32x16_bf16(pa, vf, ctx[nb], 0, 0, 0);
        }
        __builtin_amdgcn_s_setprio(0);
      }
    }
  }

  // ---- epilogue: normalize, write context [B,H,S,HD] + attn_output [B,S,D] ----
  #pragma unroll
  for (int r = 0; r < 16; ++r) {
    const float inv = 1.0f / lsum[r];
    const int qrow = q0 + (r & 3) + 8 * (r >> 2) + 4 * hi;
    #pragma unroll
    for (int nb = 0; nb < 2; ++nb) {
      const int hd = nb * 32 + l31;
      const float val = ctx[nb][r] * inv;
      out[((size_t)bh * Ss + qrow) * 64 + hd] = val;
      out[CTX_ELEMS + (((size_t)(b * Ss + qrow)) << 10) + (h << 6) + hd] = val;
    }
  }
}

// ---------------------------------------------------------------------------
extern "C" void kernel_launch(void* const* d_in, const int* in_sizes, int n_in,
                              void* d_out, int out_size, void* d_ws, size_t ws_size,
                              hipStream_t stream) {
  const float* q  = (const float*)d_in[0];
  const float* k  = (const float*)d_in[1];
  const float* v  = (const float*)d_in[2];
  const float* wq = (const float*)d_in[3];
  const float* bq = (const float*)d_in[4];
  const float* wk = (const float*)d_in[5];
  const float* bk = (const float*)d_in[6];
  const float* wv = (const float*)d_in[7];
  const float* bv = (const float*)d_in[8];
  unsigned short* ws = (unsigned short*)d_ws;
  float* out = (float*)d_out;

  if (ws_size >= WS_NEED) {
    convert_bf16<<<dim3(256, 6), 256, 0, stream>>>(q, k, v, wq, wk, wv, ws);
    qkv_gemm_bf16<<<dim3(256, 3), 256, 0, stream>>>(ws, bq, bk, bv, ws + OFF_O);
    attn_fwd<<<dim3(16, 32), 256, 0, stream>>>(ws + OFF_O, ws + OFF_O + XE, ws + OFF_O + 2 * XE, out);
  } else {
    qkv_gemm_f32<<<dim3(256, 3), 256, 0, stream>>>(q, k, v, wq, wk, wv, bq, bk, bv, ws);
    attn_fwd<<<dim3(16, 32), 256, 0, stream>>>(ws, ws + XE, ws + 2 * XE, out);
  }
}